// Round 11
// baseline (476.471 us; speedup 1.0000x reference)
//
#include <hip/hip_runtime.h>

#define Bc 16
#define Cc 512
#define Tc 2048
#define QTJ 32    // j per attn block
#define KTI 128   // i per attn iteration
#define PST2 136  // attn P row stride (ushort), 128+8
#define LTS 66    // kqv LDS transposed-tile row stride (ushort), 64+2 pad
#define EPR 36    // epilogue row stride (floats), 32+4

typedef __attribute__((ext_vector_type(8))) short short8;
typedef __attribute__((ext_vector_type(4))) float f32x4;
typedef unsigned short u16;

static __device__ __forceinline__ u16 f2bf(float x) {
  unsigned u = __float_as_uint(x);
  u += 0x7FFF + ((u >> 16) & 1);   // RNE
  return (u16)(u >> 16);
}

// Pack 2 f32 -> 2 bf16 in one VALU op (no builtin on gfx950).
static __device__ __forceinline__ unsigned cvt_pk_bf16(float lo, float hi) {
  unsigned r;
  asm("v_cvt_pk_bf16_f32 %0, %1, %2" : "=v"(r) : "v"(lo), "v"(hi));
  return r;
}

// Barrier that waits ONLY on LDS ops (lgkmcnt) — outstanding global loads
// stay in flight across it.
static __device__ __forceinline__ void block_sync_lds() {
  __builtin_amdgcn_sched_barrier(0);
  asm volatile("s_waitcnt lgkmcnt(0)" ::: "memory");
  __builtin_amdgcn_s_barrier();
  __builtin_amdgcn_sched_barrier(0);
}

// ---------------- Kernel 0: W -> bf16 (fused k||q), bias -> bkq ----------------
__global__ __launch_bounds__(256) void prep_kernel(
    const float* __restrict__ Wk, const float* __restrict__ Wq,
    const float* __restrict__ bk, const float* __restrict__ bq,
    u16* __restrict__ Wbf, float* __restrict__ bkq)
{
  int idx  = blockIdx.x * 256 + threadIdx.x;
  int base = idx * 4;
  if (base < 128 * Cc) {
    int ch = base >> 9;
    int c  = base & (Cc - 1);
    const float* src = (ch < 64) ? (Wk + (size_t)ch * Cc + c)
                                 : (Wq + (size_t)(ch - 64) * Cc + c);
    f32x4 w = *reinterpret_cast<const f32x4*>(src);
    uint2 o;
    o.x = (unsigned)f2bf(w[0]) | ((unsigned)f2bf(w[1]) << 16);
    o.y = (unsigned)f2bf(w[2]) | ((unsigned)f2bf(w[3]) << 16);
    *reinterpret_cast<uint2*>(Wbf + base) = o;
  }
  if (idx < 128) bkq[idx] = (idx < 64) ? bk[idx] : bq[idx - 64];
}

// ---------------- Kernel 1: kq[t][ch] via MFMA + vbf16 emission ----------------
__global__ __launch_bounds__(256) void kqv_kernel(
    const float* __restrict__ v, const u16* __restrict__ Wbf,
    const float* __restrict__ bkq, u16* __restrict__ kq, u16* __restrict__ vbf)
{
  __shared__ u16 LDSt[2][64][LTS];   // [buf][t][c] transposed bf16 tile
  const int b   = blockIdx.y;
  const int t0  = blockIdx.x * 64;
  const int tid = threadIdx.x;
  const int lane = tid & 63;
  const int w    = tid >> 6;     // 0..3
  const int l15  = lane & 15;
  const int lg   = lane >> 4;

  f32x4 acc[8];
  #pragma unroll
  for (int mt = 0; mt < 8; ++mt) acc[mt] = f32x4{0.f, 0.f, 0.f, 0.f};

  const float* vb = v + (size_t)b * Cc * Tc + t0;
  float x[16];
  #pragma unroll
  for (int r = 0; r < 16; ++r) x[r] = vb[(size_t)(w * 16 + r) * Tc + lane];

  int buf = 0;
  for (int c0 = 0; c0 < Cc; c0 += 64, buf ^= 1) {
    #pragma unroll
    for (int r = 0; r < 16; ++r) {
      u16 hb = f2bf(x[r]);
      LDSt[buf][lane][w * 16 + r] = hb;
      vbf[((size_t)b * Cc + c0 + w * 16 + r) * Tc + t0 + lane] = hb;
    }
    block_sync_lds();
    if (c0 + 64 < Cc) {
      #pragma unroll
      for (int r = 0; r < 16; ++r)
        x[r] = vb[(size_t)(c0 + 64 + w * 16 + r) * Tc + lane];
    }
    #pragma unroll
    for (int ks = 0; ks < 2; ++ks) {
      short8 bfrag = *reinterpret_cast<const short8*>(&LDSt[buf][w * 16 + l15][ks * 32 + lg * 8]);
      #pragma unroll
      for (int mt = 0; mt < 8; ++mt) {
        short8 afrag = *reinterpret_cast<const short8*>(
            Wbf + (size_t)(mt * 16 + l15) * Cc + c0 + ks * 32 + lg * 8);
        acc[mt] = __builtin_amdgcn_mfma_f32_16x16x32_bf16(afrag, bfrag, acc[mt], 0, 0, 0);
      }
    }
  }
  const int t = t0 + w * 16 + l15;
  u16* op = kq + ((size_t)b * Tc + t) * 128;
  #pragma unroll
  for (int mt = 0; mt < 8; ++mt) {
    int chb = mt * 16 + lg * 4;
    uint2 o;
    o.x = cvt_pk_bf16(acc[mt][0] + bkq[chb + 0], acc[mt][1] + bkq[chb + 1]);
    o.y = cvt_pk_bf16(acc[mt][2] + bkq[chb + 2], acc[mt][3] + bkq[chb + 3]);
    *reinterpret_cast<uint2*>(op + chb) = o;
  }
}

// ---------------- Kernel 2: flash attention, fixed-m, small decoupled blocks ----------------
// 4-wave blocks (32 j x all 512 c), KTI=128 per iteration, ONE lgkm-only barrier
// per iteration. Wave = (jt = wid&1: 16-j S slice, ih = wid>>1: 64-i S half) and
// c0 = wid*128 PV channel slice. 3-4 independent blocks/CU decorrelate phases.
__global__ __launch_bounds__(256, 3) void attn_kernel(
    const float* __restrict__ v, const u16* __restrict__ vbf,
    const u16* __restrict__ kq, const float* __restrict__ gamma_p,
    float* __restrict__ out)
{
  __shared__ u16 P[2][QTJ * PST2];     // 17408 B; epilogue aliases as float
  __shared__ float lsum2[2][QTJ];
  __shared__ float linv_lds[QTJ];

  // Bijective XCD swizzle: 1024 blocks, 8 XCDs -> each XCD sees 2 consecutive b's
  const int L   = blockIdx.x;
  const int lin = (L & 7) * 128 + (L >> 3);
  const int b   = lin >> 6;
  const int j0  = (lin & 63) * QTJ;
  const int tid = threadIdx.x;
  const int lane = tid & 63;
  const int wid  = tid >> 6;      // 0..3
  const int l15  = lane & 15;
  const int lg   = lane >> 4;     // 0..3
  const int jt   = wid & 1;       // S j-slice (16 j)
  const int ih   = wid >> 1;      // S i-half (64 i)
  const int c0   = wid * 128;     // PV channel slice

  short8 qf0, qf1;
  {
    const u16* qp = kq + (size_t)(b * Tc + j0 + jt * 16 + l15) * 128 + 64 + lg * 8;
    qf0 = *reinterpret_cast<const short8*>(qp);
    qf1 = *reinterpret_cast<const short8*>(qp + 32);
  }

  f32x4 O[8][2];   // [ct][jj]  128 ch x 32 j  = 64 VGPR
  #pragma unroll
  for (int a = 0; a < 8; ++a)
    #pragma unroll
    for (int bb = 0; bb < 2; ++bb) O[a][bb] = f32x4{0.f, 0.f, 0.f, 0.f};

  float lsum = 0.f;   // lane-local partial over this wave's i-half

  const u16* kbase = kq + (size_t)b * Tc * 128 + lg * 8;
  const u16* vbase = vbf + ((size_t)b * Cc + c0) * Tc;

  // prologue: kf <- K_0 for own i-half
  short8 kf[4][2];
  #pragma unroll
  for (int it = 0; it < 4; ++it) {
    const u16* kp = kbase + (size_t)(ih * 64 + it * 16 + l15) * 128;
    kf[it][0] = *reinterpret_cast<const short8*>(kp);
    kf[it][1] = *reinterpret_cast<const short8*>(kp + 32);
  }

  int pb = 0;
  for (int i0 = 0; i0 < Tc; i0 += KTI, pb ^= 1) {
    // ---- S_i for (jt, ih) from prefetched kf ----
    f32x4 sacc[4];
    #pragma unroll
    for (int it = 0; it < 4; ++it) {
      f32x4 s = f32x4{0.f, 0.f, 0.f, 0.f};
      s = __builtin_amdgcn_mfma_f32_16x16x32_bf16(kf[it][0], qf0, s, 0, 0, 0);
      s = __builtin_amdgcn_mfma_f32_16x16x32_bf16(kf[it][1], qf1, s, 0, 0, 0);
      sacc[it] = s;
    }
    // ---- prefetch K_{i+1} (in flight across barrier + PV) ----
    if (i0 + KTI < Tc) {
      #pragma unroll
      for (int it = 0; it < 4; ++it) {
        const u16* kp = kbase + (size_t)(i0 + KTI + ih * 64 + it * 16 + l15) * 128;
        kf[it][0] = *reinterpret_cast<const short8*>(kp);
        kf[it][1] = *reinterpret_cast<const short8*>(kp + 32);
      }
    }
    // ---- p = exp(s) (fixed m=0), pack, publish own P region ----
    {
      u16* prow = &P[pb][(jt * 16 + l15) * PST2 + ih * 64];
      #pragma unroll
      for (int it = 0; it < 4; ++it) {
        float p0 = __expf(sacc[it][0]);
        float p1 = __expf(sacc[it][1]);
        float p2 = __expf(sacc[it][2]);
        float p3 = __expf(sacc[it][3]);
        lsum += (p0 + p1) + (p2 + p3);
        uint2 wv;
        wv.x = cvt_pk_bf16(p0, p1);
        wv.y = cvt_pk_bf16(p2, p3);
        *reinterpret_cast<uint2*>(prow + it * 16 + lg * 4) = wv;
      }
    }
    block_sync_lds();   // the ONLY barrier per 128-i iteration

    // ---- PV_i: O[c,j] += V[c,i] P[i,j], 4 x 32-i chunks ----
    __builtin_amdgcn_s_setprio(1);
    #pragma unroll
    for (int is = 0; is < 4; ++is) {
      short8 vf[8];
      #pragma unroll
      for (int ct = 0; ct < 8; ++ct)
        vf[ct] = *reinterpret_cast<const short8*>(
            vbase + (size_t)(ct * 16 + l15) * Tc + i0 + is * 32 + lg * 8);
      short8 pf[2];
      #pragma unroll
      for (int jj = 0; jj < 2; ++jj)
        pf[jj] = *reinterpret_cast<const short8*>(
            &P[pb][(jj * 16 + l15) * PST2 + is * 32 + lg * 8]);
      #pragma unroll
      for (int ct = 0; ct < 8; ++ct)
        #pragma unroll
        for (int jj = 0; jj < 2; ++jj)
          O[ct][jj] = __builtin_amdgcn_mfma_f32_16x16x32_bf16(vf[ct], pf[jj], O[ct][jj], 0, 0, 0);
    }
    __builtin_amdgcn_s_setprio(0);
  }

  // ---- denominators: reduce lane partials, combine the two i-halves ----
  lsum += __shfl_xor(lsum, 16);
  lsum += __shfl_xor(lsum, 32);
  if (lane < 16) lsum2[ih][jt * 16 + lane] = lsum;
  __syncthreads();
  const float gamma = *gamma_p;
  if (tid < QTJ) linv_lds[tid] = gamma / (lsum2[0][tid] + lsum2[1][tid]);
  __syncthreads();

  // ---- vectorized epilogue: per-wave LDS transpose (aliases P), float4 I/O ----
  float* ep = reinterpret_cast<float*>(&P[0][0]) + wid * (16 * EPR);
  const int rd_ch = lane & 7;    // f4 chunk along j (0..7)
  const int rd_rw = lane >> 3;   // c row (0..7), +8 for second half

  #pragma unroll
  for (int ct = 0; ct < 8; ++ct) {
    // stage this ct's 16c x 32j
    #pragma unroll
    for (int jj = 0; jj < 2; ++jj)
      #pragma unroll
      for (int rr = 0; rr < 4; ++rr)
        ep[(lg * 4 + rr) * EPR + jj * 16 + l15] = O[ct][jj][rr];
    __builtin_amdgcn_sched_barrier(0);
    // read back float4-along-j, fuse residual + scale, coalesced global I/O
    #pragma unroll
    for (int h = 0; h < 2; ++h) {
      const int rw = rd_rw + 8 * h;
      const int c_glob = c0 + ct * 16 + rw;
      const float* vrow = v + ((size_t)(b * Cc + c_glob)) * Tc + j0;
      float* orow = out + ((size_t)(b * Cc + c_glob)) * Tc + j0;
      const int jf = rd_ch * 4;
      f32x4 o4 = *reinterpret_cast<const f32x4*>(&ep[rw * EPR + jf]);
      f32x4 li = *reinterpret_cast<const f32x4*>(&linv_lds[jf]);
      f32x4 v4 = *reinterpret_cast<const f32x4*>(&vrow[jf]);
      f32x4 o;
      o[0] = v4[0] + li[0] * o4[0];
      o[1] = v4[1] + li[1] * o4[1];
      o[2] = v4[2] + li[2] * o4[2];
      o[3] = v4[3] + li[3] * o4[3];
      *reinterpret_cast<f32x4*>(&orow[jf]) = o;
    }
    __builtin_amdgcn_sched_barrier(0);
  }
}

extern "C" void kernel_launch(void* const* d_in, const int* in_sizes, int n_in,
                              void* d_out, int out_size, void* d_ws, size_t ws_size,
                              hipStream_t stream) {
  const float* v  = (const float*)d_in[0];
  const float* Wk = (const float*)d_in[1];
  const float* bk = (const float*)d_in[2];
  const float* Wq = (const float*)d_in[3];
  const float* bq = (const float*)d_in[4];
  const float* gm = (const float*)d_in[5];
  float* out = (float*)d_out;

  char* ws = (char*)d_ws;
  u16*   kqb = (u16*)ws;                                   //  8,388,608 B
  u16*   vbf = (u16*)(ws + 8388608);                       // 33,554,432 B
  u16*   Wbf = (u16*)(ws + 8388608 + 33554432);            //    131,072 B
  float* bkq = (float*)(ws + 8388608 + 33554432 + 131072); //        512 B

  prep_kernel<<<dim3(64), dim3(256), 0, stream>>>(Wk, Wq, bk, bq, Wbf, bkq);
  kqv_kernel<<<dim3(Tc / 64, Bc), dim3(256), 0, stream>>>(v, Wbf, bkq, kqb, vbf);
  attn_kernel<<<dim3((Tc / QTJ) * Bc), dim3(256), 0, stream>>>(v, vbf, kqb, gm, out);
}

// Round 12
// 341.292 us; speedup vs baseline: 1.3961x; 1.3961x over previous
//
#include <hip/hip_runtime.h>

#define Bc 16
#define Cc 512
#define Tc 2048
#define QT 128
#define LTS 66    // kqv LDS transposed-tile row stride (ushort), 64+2 pad

typedef __attribute__((ext_vector_type(8)))  short short8;
typedef __attribute__((ext_vector_type(4)))  float f32x4;
typedef __attribute__((ext_vector_type(16))) float f32x16;
typedef __attribute__((ext_vector_type(4)))  unsigned u32x4;
typedef unsigned short u16;

static __device__ __forceinline__ u16 f2bf(float x) {
  unsigned u = __float_as_uint(x);
  u += 0x7FFF + ((u >> 16) & 1);   // RNE
  return (u16)(u >> 16);
}

// Pack 2 f32 -> 2 bf16 in one VALU op (no builtin on gfx950).
static __device__ __forceinline__ unsigned cvt_pk_bf16(float lo, float hi) {
  unsigned r;
  asm("v_cvt_pk_bf16_f32 %0, %1, %2" : "=v"(r) : "v"(lo), "v"(hi));
  return r;
}

// v_permlane32_swap_b32 a, b: a_hi <-> b_lo.
// After: a = {a_lo, b_lo_old}, b = {a_hi_old, b_hi}.
static __device__ __forceinline__ void permlane32_swap(unsigned& a, unsigned& b) {
  asm volatile("v_permlane32_swap_b32 %0, %1" : "+v"(a), "+v"(b));
}

static __device__ __forceinline__ void block_sync_lds() {
  __builtin_amdgcn_sched_barrier(0);
  asm volatile("s_waitcnt lgkmcnt(0)" ::: "memory");
  __builtin_amdgcn_s_barrier();
  __builtin_amdgcn_sched_barrier(0);
}

// ---------------- Kernel 0: W -> bf16 (fused k||q), bias -> bkq ----------------
__global__ __launch_bounds__(256) void prep_kernel(
    const float* __restrict__ Wk, const float* __restrict__ Wq,
    const float* __restrict__ bk, const float* __restrict__ bq,
    u16* __restrict__ Wbf, float* __restrict__ bkq)
{
  int idx  = blockIdx.x * 256 + threadIdx.x;
  int base = idx * 4;
  if (base < 128 * Cc) {
    int ch = base >> 9;
    int c  = base & (Cc - 1);
    const float* src = (ch < 64) ? (Wk + (size_t)ch * Cc + c)
                                 : (Wq + (size_t)(ch - 64) * Cc + c);
    f32x4 w = *reinterpret_cast<const f32x4*>(src);
    uint2 o;
    o.x = (unsigned)f2bf(w[0]) | ((unsigned)f2bf(w[1]) << 16);
    o.y = (unsigned)f2bf(w[2]) | ((unsigned)f2bf(w[3]) << 16);
    *reinterpret_cast<uint2*>(Wbf + base) = o;
  }
  if (idx < 128) bkq[idx] = (idx < 64) ? bk[idx] : bq[idx - 64];
}

// ---------------- Kernel 1: kq[t][ch] via MFMA + vbf16 emission ----------------
__global__ __launch_bounds__(256) void kqv_kernel(
    const float* __restrict__ v, const u16* __restrict__ Wbf,
    const float* __restrict__ bkq, u16* __restrict__ kq, u16* __restrict__ vbf)
{
  __shared__ u16 LDSt[2][64][LTS];
  const int b   = blockIdx.y;
  const int t0  = blockIdx.x * 64;
  const int tid = threadIdx.x;
  const int lane = tid & 63;
  const int w    = tid >> 6;
  const int l15  = lane & 15;
  const int lg   = lane >> 4;

  f32x4 acc[8];
  #pragma unroll
  for (int mt = 0; mt < 8; ++mt) acc[mt] = f32x4{0.f, 0.f, 0.f, 0.f};

  const float* vb = v + (size_t)b * Cc * Tc + t0;
  float x[16];
  #pragma unroll
  for (int r = 0; r < 16; ++r) x[r] = vb[(size_t)(w * 16 + r) * Tc + lane];

  int buf = 0;
  for (int c0 = 0; c0 < Cc; c0 += 64, buf ^= 1) {
    #pragma unroll
    for (int r = 0; r < 16; ++r) {
      u16 hb = f2bf(x[r]);
      LDSt[buf][lane][w * 16 + r] = hb;
      vbf[((size_t)b * Cc + c0 + w * 16 + r) * Tc + t0 + lane] = hb;
    }
    block_sync_lds();
    if (c0 + 64 < Cc) {
      #pragma unroll
      for (int r = 0; r < 16; ++r)
        x[r] = vb[(size_t)(c0 + 64 + w * 16 + r) * Tc + lane];
    }
    #pragma unroll
    for (int ks = 0; ks < 2; ++ks) {
      short8 bfrag = *reinterpret_cast<const short8*>(&LDSt[buf][w * 16 + l15][ks * 32 + lg * 8]);
      #pragma unroll
      for (int mt = 0; mt < 8; ++mt) {
        short8 afrag = *reinterpret_cast<const short8*>(
            Wbf + (size_t)(mt * 16 + l15) * Cc + c0 + ks * 32 + lg * 8);
        acc[mt] = __builtin_amdgcn_mfma_f32_16x16x32_bf16(afrag, bfrag, acc[mt], 0, 0, 0);
      }
    }
  }
  const int t = t0 + w * 16 + l15;
  u16* op = kq + ((size_t)b * Tc + t) * 128;
  #pragma unroll
  for (int mt = 0; mt < 8; ++mt) {
    int chb = mt * 16 + lg * 4;
    uint2 o;
    o.x = cvt_pk_bf16(acc[mt][0] + bkq[chb + 0], acc[mt][1] + bkq[chb + 1]);
    o.y = cvt_pk_bf16(acc[mt][2] + bkq[chb + 2], acc[mt][3] + bkq[chb + 3]);
    *reinterpret_cast<uint2*>(op + chb) = o;
  }
}

// ---------------- Kernel 2: barrier-free 32x32 swapped-operand flash attention ----------------
// 8 waves: jt = wid&1 (64-j group), cg = wid>>1 (128-c group).
// S^T = mfma32(K, Q): lane owns col j = lane&31; rows i = (reg&3)+8*(reg>>2)+4*(lane>>5).
// P stays in registers: exp -> cvt_pk -> permlane32_swap -> PV A-fragments.
// PV: O[j][c] = mfma32(P_frag, V_frag). NO LDS / NO barriers in the main loop.
__global__ __launch_bounds__(512, 2) void attn_kernel(
    const float* __restrict__ v, const u16* __restrict__ vbf,
    const u16* __restrict__ kq, const float* __restrict__ gamma_p,
    float* __restrict__ out)
{
  __shared__ __align__(16) float ep[8][32 * 36];   // per-wave epilogue transpose
  __shared__ float lsum_lds[QT];
  __shared__ __align__(16) float linv_lds[QT];

  // XCD-aware swizzle: 256 blocks, 8 XCDs -> each XCD sees 2 consecutive b's
  const int L   = blockIdx.x;
  const int lin = (L & 7) * 32 + (L >> 3);
  const int b   = lin >> 4;
  const int j0  = (lin & 15) * QT;
  const int tid = threadIdx.x;
  const int lane = tid & 63;
  const int wid  = tid >> 6;      // 0..7
  const int l31  = lane & 31;
  const int kh   = lane >> 5;     // 0..1
  const int jt   = wid & 1;       // 64-j group
  const int cg   = wid >> 1;      // 128-c group
  const int j0w  = j0 + jt * 64;
  const int c0w  = cg * 128;

  // Q B-fragments: B[n=j][k=d], n = l31, k = ks*16 + kh*8 + e
  short8 qf[2][4];
  #pragma unroll
  for (int jt2 = 0; jt2 < 2; ++jt2)
    #pragma unroll
    for (int ks = 0; ks < 4; ++ks)
      qf[jt2][ks] = *reinterpret_cast<const short8*>(
          kq + (size_t)(b * Tc + j0w + jt2 * 32 + l31) * 128 + 64 + ks * 16 + kh * 8);

  f32x16 O[2][4];   // [jt2][cc]: rows j (16/lane), col c = l31 within chunk
  #pragma unroll
  for (int a = 0; a < 2; ++a)
    #pragma unroll
    for (int bb = 0; bb < 4; ++bb)
      #pragma unroll
      for (int e = 0; e < 16; ++e) O[a][bb][e] = 0.f;

  float ls0 = 0.f, ls1 = 0.f;

  const u16* kbase = kq + (size_t)b * Tc * 128;
  const u16* vbase = vbf + ((size_t)b * Cc + c0w) * Tc;

  for (int i0 = 0; i0 < Tc; i0 += 64) {
    #pragma unroll
    for (int it2 = 0; it2 < 2; ++it2) {
      const int ib = i0 + it2 * 32;
      // K A-fragments: A[m=i][k=d], m = l31 (shared by all 8 waves -> L1)
      short8 kf[4];
      #pragma unroll
      for (int ks = 0; ks < 4; ++ks)
        kf[ks] = *reinterpret_cast<const short8*>(
            kbase + (size_t)(ib + l31) * 128 + ks * 16 + kh * 8);
      // V B-fragments: B[n=c][k=i], n = l31; issued early, used after S+exp
      short8 vfr[4][2];
      #pragma unroll
      for (int cc = 0; cc < 4; ++cc)
        #pragma unroll
        for (int kc = 0; kc < 2; ++kc)
          vfr[cc][kc] = *reinterpret_cast<const short8*>(
              vbase + (size_t)(cc * 32 + l31) * Tc + ib + kc * 16 + kh * 8);

      #pragma unroll
      for (int jt2 = 0; jt2 < 2; ++jt2) {
        // ---- S^T tile: D[m=i][n=j] ----
        f32x16 s;
        #pragma unroll
        for (int e = 0; e < 16; ++e) s[e] = 0.f;
        #pragma unroll
        for (int ks = 0; ks < 4; ++ks)
          s = __builtin_amdgcn_mfma_f32_32x32x16_bf16(kf[ks], qf[jt2][ks], s, 0, 0, 0);

        // ---- p = exp(s) (fixed m=0), lane-local denominator ----
        float p[16];
        float psum = 0.f;
        #pragma unroll
        for (int e = 0; e < 16; ++e) { p[e] = __expf(s[e]); psum += p[e]; }
        if (jt2 == 0) ls0 += psum; else ls1 += psum;

        // ---- build PV A-fragments in-register (cvt_pk + permlane32_swap) ----
        // rows held: lo lane {0-3,8-11,16-19,24-27}, hi lane +4.
        unsigned x  = cvt_pk_bf16(p[0],  p[1]);   // i(0,1)   | i(4,5)
        unsigned y  = cvt_pk_bf16(p[2],  p[3]);   // i(2,3)   | i(6,7)
        unsigned z  = cvt_pk_bf16(p[4],  p[5]);   // i(8,9)   | i(12,13)
        unsigned w  = cvt_pk_bf16(p[6],  p[7]);   // i(10,11) | i(14,15)
        permlane32_swap(x, z);   // x: lo i(0,1)  hi i(8,9)  ; z: lo i(4,5)  hi i(12,13)
        permlane32_swap(y, w);   // y: lo i(2,3)  hi i(10,11); w: lo i(6,7)  hi i(14,15)
        u32x4 t0v = u32x4{x, y, z, w};
        short8 pa0 = *reinterpret_cast<short8*>(&t0v);   // k = kh*8+e over i 0..15
        unsigned x2 = cvt_pk_bf16(p[8],  p[9]);
        unsigned y2 = cvt_pk_bf16(p[10], p[11]);
        unsigned z2 = cvt_pk_bf16(p[12], p[13]);
        unsigned w2 = cvt_pk_bf16(p[14], p[15]);
        permlane32_swap(x2, z2);
        permlane32_swap(y2, w2);
        u32x4 t1v = u32x4{x2, y2, z2, w2};
        short8 pa1 = *reinterpret_cast<short8*>(&t1v);   // i 16..31

        // ---- PV: O[j][c] += P[j,i] V[c,i] ----
        #pragma unroll
        for (int cc = 0; cc < 4; ++cc) {
          O[jt2][cc] = __builtin_amdgcn_mfma_f32_32x32x16_bf16(pa0, vfr[cc][0], O[jt2][cc], 0, 0, 0);
          O[jt2][cc] = __builtin_amdgcn_mfma_f32_32x32x16_bf16(pa1, vfr[cc][1], O[jt2][cc], 0, 0, 0);
        }
      }
    }
  }

  // ---- denominators: lanes L,L+32 share j; combine halves ----
  float t0s = ls0 + __shfl_xor(ls0, 32);
  float t1s = ls1 + __shfl_xor(ls1, 32);
  if (cg == 0 && lane < 32) {
    lsum_lds[jt * 64 + lane]      = t0s;
    lsum_lds[jt * 64 + 32 + lane] = t1s;
  }
  __syncthreads();
  const float gamma = *gamma_p;
  if (tid < QT) linv_lds[tid] = gamma / lsum_lds[tid];
  __syncthreads();

  // ---- epilogue: per-wave LDS transpose [c 32][j stride 36], float4 global I/O ----
  float* epw = ep[wid];
  #pragma unroll
  for (int jt2 = 0; jt2 < 2; ++jt2) {
    #pragma unroll
    for (int cc = 0; cc < 4; ++cc) {
      #pragma unroll
      for (int reg = 0; reg < 16; ++reg) {
        int jr = (reg & 3) + 8 * (reg >> 2) + 4 * kh;
        epw[l31 * 36 + jr] = O[jt2][cc][reg];
      }
      asm volatile("s_waitcnt lgkmcnt(0)" ::: "memory");
      __builtin_amdgcn_sched_barrier(0);
      #pragma unroll
      for (int t = 0; t < 4; ++t) {
        const int cr = (lane >> 3) + 8 * t;
        const int ch = lane & 7;
        f32x4 o4 = *reinterpret_cast<const f32x4*>(&epw[cr * 36 + ch * 4]);
        const int jg = jt * 64 + jt2 * 32 + ch * 4;
        f32x4 li = *reinterpret_cast<const f32x4*>(&linv_lds[jg]);
        const int c_glob = c0w + cc * 32 + cr;
        const float* vrow = v + ((size_t)(b * Cc + c_glob)) * Tc + j0 + jg;
        float* orow = out + ((size_t)(b * Cc + c_glob)) * Tc + j0 + jg;
        f32x4 v4 = *reinterpret_cast<const f32x4*>(vrow);
        f32x4 o;
        o[0] = v4[0] + li[0] * o4[0];
        o[1] = v4[1] + li[1] * o4[1];
        o[2] = v4[2] + li[2] * o4[2];
        o[3] = v4[3] + li[3] * o4[3];
        *reinterpret_cast<f32x4*>(orow) = o;
      }
      asm volatile("s_waitcnt lgkmcnt(0)" ::: "memory");
      __builtin_amdgcn_sched_barrier(0);
    }
  }
}

extern "C" void kernel_launch(void* const* d_in, const int* in_sizes, int n_in,
                              void* d_out, int out_size, void* d_ws, size_t ws_size,
                              hipStream_t stream) {
  const float* v  = (const float*)d_in[0];
  const float* Wk = (const float*)d_in[1];
  const float* bk = (const float*)d_in[2];
  const float* Wq = (const float*)d_in[3];
  const float* bq = (const float*)d_in[4];
  const float* gm = (const float*)d_in[5];
  float* out = (float*)d_out;

  char* ws = (char*)d_ws;
  u16*   kqb = (u16*)ws;                                   //  8,388,608 B
  u16*   vbf = (u16*)(ws + 8388608);                       // 33,554,432 B
  u16*   Wbf = (u16*)(ws + 8388608 + 33554432);            //    131,072 B
  float* bkq = (float*)(ws + 8388608 + 33554432 + 131072); //        512 B

  prep_kernel<<<dim3(64), dim3(256), 0, stream>>>(Wk, Wq, bk, bq, Wbf, bkq);
  kqv_kernel<<<dim3(Tc / 64, Bc), dim3(256), 0, stream>>>(v, Wbf, bkq, kqb, vbf);
  attn_kernel<<<dim3((Tc / QT) * Bc), dim3(512), 0, stream>>>(v, vbf, kqb, gm, out);
}

// Round 13
// 315.339 us; speedup vs baseline: 1.5110x; 1.0823x over previous
//
#include <hip/hip_runtime.h>

#define Bc 16
#define Cc 512
#define Tc 2048
#define QT 128
#define KT 128
#define PST2 136  // P row stride (ushort), 128+8
#define LTS 66    // kqv LDS transposed-tile row stride (ushort), 64+2 pad
#define EPS 132   // epilogue LDS row stride (floats), 128+4

typedef __attribute__((ext_vector_type(8))) short short8;
typedef __attribute__((ext_vector_type(4))) float f32x4;
typedef unsigned short u16;

static __device__ __forceinline__ u16 f2bf(float x) {
  unsigned u = __float_as_uint(x);
  u += 0x7FFF + ((u >> 16) & 1);   // RNE
  return (u16)(u >> 16);
}

// Pack 2 f32 -> 2 bf16 in one VALU op (no builtin on gfx950).
static __device__ __forceinline__ unsigned cvt_pk_bf16(float lo, float hi) {
  unsigned r;
  asm("v_cvt_pk_bf16_f32 %0, %1, %2" : "=v"(r) : "v"(lo), "v"(hi));
  return r;
}

// Barrier that waits ONLY on LDS ops (lgkmcnt) — outstanding global loads
// stay in flight across it.
static __device__ __forceinline__ void block_sync_lds() {
  __builtin_amdgcn_sched_barrier(0);
  asm volatile("s_waitcnt lgkmcnt(0)" ::: "memory");
  __builtin_amdgcn_s_barrier();
  __builtin_amdgcn_sched_barrier(0);
}

// ---------------- Kernel 0: W -> bf16 (fused k||q), bias -> bkq ----------------
__global__ __launch_bounds__(256) void prep_kernel(
    const float* __restrict__ Wk, const float* __restrict__ Wq,
    const float* __restrict__ bk, const float* __restrict__ bq,
    u16* __restrict__ Wbf, float* __restrict__ bkq)
{
  int idx  = blockIdx.x * 256 + threadIdx.x;
  int base = idx * 4;
  if (base < 128 * Cc) {
    int ch = base >> 9;
    int c  = base & (Cc - 1);
    const float* src = (ch < 64) ? (Wk + (size_t)ch * Cc + c)
                                 : (Wq + (size_t)(ch - 64) * Cc + c);
    f32x4 w = *reinterpret_cast<const f32x4*>(src);
    uint2 o;
    o.x = (unsigned)f2bf(w[0]) | ((unsigned)f2bf(w[1]) << 16);
    o.y = (unsigned)f2bf(w[2]) | ((unsigned)f2bf(w[3]) << 16);
    *reinterpret_cast<uint2*>(Wbf + base) = o;
  }
  if (idx < 128) bkq[idx] = (idx < 64) ? bk[idx] : bq[idx - 64];
}

// ---------------- Kernel 1: kq[t][ch] via MFMA + vbf16 emission ----------------
__global__ __launch_bounds__(256) void kqv_kernel(
    const float* __restrict__ v, const u16* __restrict__ Wbf,
    const float* __restrict__ bkq, u16* __restrict__ kq, u16* __restrict__ vbf)
{
  __shared__ u16 LDSt[2][64][LTS];
  const int b   = blockIdx.y;
  const int t0  = blockIdx.x * 64;
  const int tid = threadIdx.x;
  const int lane = tid & 63;
  const int w    = tid >> 6;
  const int l15  = lane & 15;
  const int lg   = lane >> 4;

  f32x4 acc[8];
  #pragma unroll
  for (int mt = 0; mt < 8; ++mt) acc[mt] = f32x4{0.f, 0.f, 0.f, 0.f};

  const float* vb = v + (size_t)b * Cc * Tc + t0;
  float x[16];
  #pragma unroll
  for (int r = 0; r < 16; ++r) x[r] = vb[(size_t)(w * 16 + r) * Tc + lane];

  int buf = 0;
  for (int c0 = 0; c0 < Cc; c0 += 64, buf ^= 1) {
    #pragma unroll
    for (int r = 0; r < 16; ++r) {
      u16 hb = f2bf(x[r]);
      LDSt[buf][lane][w * 16 + r] = hb;
      vbf[((size_t)b * Cc + c0 + w * 16 + r) * Tc + t0 + lane] = hb;
    }
    block_sync_lds();
    if (c0 + 64 < Cc) {
      #pragma unroll
      for (int r = 0; r < 16; ++r)
        x[r] = vb[(size_t)(c0 + 64 + w * 16 + r) * Tc + lane];
    }
    #pragma unroll
    for (int ks = 0; ks < 2; ++ks) {
      short8 bfrag = *reinterpret_cast<const short8*>(&LDSt[buf][w * 16 + l15][ks * 32 + lg * 8]);
      #pragma unroll
      for (int mt = 0; mt < 8; ++mt) {
        short8 afrag = *reinterpret_cast<const short8*>(
            Wbf + (size_t)(mt * 16 + l15) * Cc + c0 + ks * 32 + lg * 8);
        acc[mt] = __builtin_amdgcn_mfma_f32_16x16x32_bf16(afrag, bfrag, acc[mt], 0, 0, 0);
      }
    }
  }
  const int t = t0 + w * 16 + l15;
  u16* op = kq + ((size_t)b * Tc + t) * 128;
  #pragma unroll
  for (int mt = 0; mt < 8; ++mt) {
    int chb = mt * 16 + lg * 4;
    uint2 o;
    o.x = cvt_pk_bf16(acc[mt][0] + bkq[chb + 0], acc[mt][1] + bkq[chb + 1]);
    o.y = cvt_pk_bf16(acc[mt][2] + bkq[chb + 2], acc[mt][3] + bkq[chb + 3]);
    *reinterpret_cast<uint2*>(op + chb) = o;
  }
}

// ---------------- Kernel 2: flash attention, fixed-m, KT=128, no setprio ----------------
// r9 phase structure, but ONE barrier per 128-i tile (half the convoy events).
// K loaded in two halves reusing kf (latency hidden under exp phases);
// V chunks ping-pong vfA/vfB so VGPR stays within the 2-wave/SIMD budget.
__global__ __launch_bounds__(512, 2) void attn_kernel(
    const float* __restrict__ v, const u16* __restrict__ vbf,
    const u16* __restrict__ kq, const float* __restrict__ gamma_p,
    float* __restrict__ out)
{
  __shared__ u16 P[2][QT * PST2];   // 69632 B; epilogue aliases P[0] as float
  __shared__ float lsum_lds[QT];
  __shared__ __align__(16) float linv_lds[QT];

  // XCD-aware swizzle: 256 blocks, 8 XCDs -> each XCD sees 2 consecutive b's
  const int L   = blockIdx.x;
  const int lin = (L & 7) * 32 + (L >> 3);
  const int b   = lin >> 4;
  const int j0  = (lin & 15) * QT;
  const int tid = threadIdx.x;
  const int lane = tid & 63;
  const int wid  = tid >> 6;      // 0..7 = owned j-tile AND channel slice
  const int l15  = lane & 15;
  const int lg   = lane >> 4;     // 0..3
  const int c0   = wid * 64;

  short8 qf0, qf1;
  {
    const u16* qp = kq + (size_t)(b * Tc + j0 + wid * 16 + l15) * 128 + 64 + lg * 8;
    qf0 = *reinterpret_cast<const short8*>(qp);
    qf1 = *reinterpret_cast<const short8*>(qp + 32);
  }

  f32x4 O[4][8];   // [ct][jj] -> AGPRs (128)
  #pragma unroll
  for (int a = 0; a < 4; ++a)
    #pragma unroll
    for (int bb = 0; bb < 8; ++bb) O[a][bb] = f32x4{0.f, 0.f, 0.f, 0.f};

  float lsum = 0.f;

  const u16* kbase = kq + (size_t)b * Tc * 128 + lg * 8;
  const u16* vbase = vbf + ((size_t)b * Cc + c0) * Tc;

  short8 kf[4][2];   // K frags, reused for each 64-i half
  short8 vfA[4], vfB[4];

  // prologue: K half0 of iter0; V chunk0 of iter0
  #pragma unroll
  for (int it = 0; it < 4; ++it) {
    const u16* kp = kbase + (size_t)(it * 16 + l15) * 128;
    kf[it][0] = *reinterpret_cast<const short8*>(kp);
    kf[it][1] = *reinterpret_cast<const short8*>(kp + 32);
  }
  #pragma unroll
  for (int ct = 0; ct < 4; ++ct)
    vfA[ct] = *reinterpret_cast<const short8*>(
        vbase + (size_t)(ct * 16 + l15) * Tc + lg * 8);

  int pb = 0;
  for (int i0 = 0; i0 < Tc; i0 += KT, pb ^= 1) {
    const bool last = (i0 + KT >= Tc);
    u16* prow = &P[pb][(wid * 16 + l15) * PST2];

    // ---- S half0 from prefetched kf ----
    f32x4 sacc[4];
    #pragma unroll
    for (int it = 0; it < 4; ++it) {
      f32x4 s = f32x4{0.f, 0.f, 0.f, 0.f};
      s = __builtin_amdgcn_mfma_f32_16x16x32_bf16(kf[it][0], qf0, s, 0, 0, 0);
      s = __builtin_amdgcn_mfma_f32_16x16x32_bf16(kf[it][1], qf1, s, 0, 0, 0);
      sacc[it] = s;
    }
    // issue K loads for half1 (covered by exp half0)
    #pragma unroll
    for (int it = 0; it < 4; ++it) {
      const u16* kp = kbase + (size_t)(i0 + 64 + it * 16 + l15) * 128;
      kf[it][0] = *reinterpret_cast<const short8*>(kp);
      kf[it][1] = *reinterpret_cast<const short8*>(kp + 32);
    }
    // exp half0 + publish P cols 0..63
    #pragma unroll
    for (int it = 0; it < 4; ++it) {
      float p0 = __expf(sacc[it][0]);
      float p1 = __expf(sacc[it][1]);
      float p2 = __expf(sacc[it][2]);
      float p3 = __expf(sacc[it][3]);
      lsum += (p0 + p1) + (p2 + p3);
      uint2 wv;
      wv.x = cvt_pk_bf16(p0, p1);
      wv.y = cvt_pk_bf16(p2, p3);
      *reinterpret_cast<uint2*>(prow + it * 16 + lg * 4) = wv;
    }

    // ---- S half1 ----
    #pragma unroll
    for (int it = 0; it < 4; ++it) {
      f32x4 s = f32x4{0.f, 0.f, 0.f, 0.f};
      s = __builtin_amdgcn_mfma_f32_16x16x32_bf16(kf[it][0], qf0, s, 0, 0, 0);
      s = __builtin_amdgcn_mfma_f32_16x16x32_bf16(kf[it][1], qf1, s, 0, 0, 0);
      sacc[it] = s;
    }
    // issue K loads for next iter half0 (covered by exp half1 + barrier + PV)
    if (!last) {
      #pragma unroll
      for (int it = 0; it < 4; ++it) {
        const u16* kp = kbase + (size_t)(i0 + KT + it * 16 + l15) * 128;
        kf[it][0] = *reinterpret_cast<const short8*>(kp);
        kf[it][1] = *reinterpret_cast<const short8*>(kp + 32);
      }
    }
    // exp half1 + publish P cols 64..127
    #pragma unroll
    for (int it = 0; it < 4; ++it) {
      float p0 = __expf(sacc[it][0]);
      float p1 = __expf(sacc[it][1]);
      float p2 = __expf(sacc[it][2]);
      float p3 = __expf(sacc[it][3]);
      lsum += (p0 + p1) + (p2 + p3);
      uint2 wv;
      wv.x = cvt_pk_bf16(p0, p1);
      wv.y = cvt_pk_bf16(p2, p3);
      *reinterpret_cast<uint2*>(prow + 64 + it * 16 + lg * 4) = wv;
    }

    block_sync_lds();   // ONE barrier per 128-i tile

    // ---- PV: 4 chunks of 32 i, V ping-pong vfA/vfB ----
    // chunk 0 (vfA), prefetch chunk 1 -> vfB
    #pragma unroll
    for (int ct = 0; ct < 4; ++ct)
      vfB[ct] = *reinterpret_cast<const short8*>(
          vbase + (size_t)(ct * 16 + l15) * Tc + i0 + 32 + lg * 8);
    {
      short8 pf[8];
      #pragma unroll
      for (int jj = 0; jj < 8; ++jj)
        pf[jj] = *reinterpret_cast<const short8*>(
            &P[pb][(jj * 16 + l15) * PST2 + lg * 8]);
      #pragma unroll
      for (int ct = 0; ct < 4; ++ct)
        #pragma unroll
        for (int jj = 0; jj < 8; ++jj)
          O[ct][jj] = __builtin_amdgcn_mfma_f32_16x16x32_bf16(vfA[ct], pf[jj], O[ct][jj], 0, 0, 0);
    }
    // chunk 1 (vfB), prefetch chunk 2 -> vfA
    #pragma unroll
    for (int ct = 0; ct < 4; ++ct)
      vfA[ct] = *reinterpret_cast<const short8*>(
          vbase + (size_t)(ct * 16 + l15) * Tc + i0 + 64 + lg * 8);
    {
      short8 pf[8];
      #pragma unroll
      for (int jj = 0; jj < 8; ++jj)
        pf[jj] = *reinterpret_cast<const short8*>(
            &P[pb][(jj * 16 + l15) * PST2 + 32 + lg * 8]);
      #pragma unroll
      for (int ct = 0; ct < 4; ++ct)
        #pragma unroll
        for (int jj = 0; jj < 8; ++jj)
          O[ct][jj] = __builtin_amdgcn_mfma_f32_16x16x32_bf16(vfB[ct], pf[jj], O[ct][jj], 0, 0, 0);
    }
    // chunk 2 (vfA), prefetch chunk 3 -> vfB
    #pragma unroll
    for (int ct = 0; ct < 4; ++ct)
      vfB[ct] = *reinterpret_cast<const short8*>(
          vbase + (size_t)(ct * 16 + l15) * Tc + i0 + 96 + lg * 8);
    {
      short8 pf[8];
      #pragma unroll
      for (int jj = 0; jj < 8; ++jj)
        pf[jj] = *reinterpret_cast<const short8*>(
            &P[pb][(jj * 16 + l15) * PST2 + 64 + lg * 8]);
      #pragma unroll
      for (int ct = 0; ct < 4; ++ct)
        #pragma unroll
        for (int jj = 0; jj < 8; ++jj)
          O[ct][jj] = __builtin_amdgcn_mfma_f32_16x16x32_bf16(vfA[ct], pf[jj], O[ct][jj], 0, 0, 0);
    }
    // chunk 3 (vfB), prefetch next-iter chunk 0 -> vfA
    if (!last) {
      #pragma unroll
      for (int ct = 0; ct < 4; ++ct)
        vfA[ct] = *reinterpret_cast<const short8*>(
            vbase + (size_t)(ct * 16 + l15) * Tc + i0 + KT + lg * 8);
    }
    {
      short8 pf[8];
      #pragma unroll
      for (int jj = 0; jj < 8; ++jj)
        pf[jj] = *reinterpret_cast<const short8*>(
            &P[pb][(jj * 16 + l15) * PST2 + 96 + lg * 8]);
      #pragma unroll
      for (int ct = 0; ct < 4; ++ct)
        #pragma unroll
        for (int jj = 0; jj < 8; ++jj)
          O[ct][jj] = __builtin_amdgcn_mfma_f32_16x16x32_bf16(vfB[ct], pf[jj], O[ct][jj], 0, 0, 0);
    }
  }

  // ---- denominators ----
  lsum += __shfl_xor(lsum, 16);
  lsum += __shfl_xor(lsum, 32);
  if (lane < 16) lsum_lds[wid * 16 + lane] = lsum;
  __syncthreads();
  const float gamma = *gamma_p;
  if (tid < QT) linv_lds[tid] = gamma / lsum_lds[tid];
  __syncthreads();

  // ---- vectorized epilogue: per-wave LDS transpose (aliases P[0]), float4 I/O ----
  float* ep = reinterpret_cast<float*>(&P[0][0]) + wid * (8 * EPS);
  const int half_sel = lg >> 1;
  const int cl_base  = (lg & 1) * 4;
  const int rd_rw = lane >> 3;   // row 0..7 (8 consecutive lanes share a row)
  const int rd_ch = lane & 7;    // f4 chunk along j

  #pragma unroll
  for (int r = 0; r < 8; ++r) {
    const int ct = r >> 1;
    const int hs = r & 1;
    if (half_sel == hs) {
      #pragma unroll
      for (int jj = 0; jj < 8; ++jj)
        #pragma unroll
        for (int rr = 0; rr < 4; ++rr)
          ep[(cl_base + rr) * EPS + jj * 16 + l15] = O[ct][jj][rr];
    }
    asm volatile("s_waitcnt lgkmcnt(0)" ::: "memory");
    __builtin_amdgcn_sched_barrier(0);
    const int c_glob = c0 + ct * 16 + hs * 8 + rd_rw;
    const float* vrow = v + ((size_t)(b * Cc + c_glob)) * Tc + j0;
    float* orow = out + ((size_t)(b * Cc + c_glob)) * Tc + j0;
    #pragma unroll
    for (int qq = 0; qq < 4; ++qq) {
      const int jf = (rd_ch + 8 * qq) * 4;
      f32x4 o4 = *reinterpret_cast<const f32x4*>(&ep[rd_rw * EPS + jf]);
      f32x4 li = *reinterpret_cast<const f32x4*>(&linv_lds[jf]);
      f32x4 v4 = *reinterpret_cast<const f32x4*>(&vrow[jf]);
      f32x4 o;
      o[0] = v4[0] + li[0] * o4[0];
      o[1] = v4[1] + li[1] * o4[1];
      o[2] = v4[2] + li[2] * o4[2];
      o[3] = v4[3] + li[3] * o4[3];
      *reinterpret_cast<f32x4*>(&orow[jf]) = o;
    }
    asm volatile("s_waitcnt lgkmcnt(0)" ::: "memory");
    __builtin_amdgcn_sched_barrier(0);
  }
}

extern "C" void kernel_launch(void* const* d_in, const int* in_sizes, int n_in,
                              void* d_out, int out_size, void* d_ws, size_t ws_size,
                              hipStream_t stream) {
  const float* v  = (const float*)d_in[0];
  const float* Wk = (const float*)d_in[1];
  const float* bk = (const float*)d_in[2];
  const float* Wq = (const float*)d_in[3];
  const float* bq = (const float*)d_in[4];
  const float* gm = (const float*)d_in[5];
  float* out = (float*)d_out;

  char* ws = (char*)d_ws;
  u16*   kqb = (u16*)ws;                                   //  8,388,608 B
  u16*   vbf = (u16*)(ws + 8388608);                       // 33,554,432 B
  u16*   Wbf = (u16*)(ws + 8388608 + 33554432);            //    131,072 B
  float* bkq = (float*)(ws + 8388608 + 33554432 + 131072); //        512 B

  prep_kernel<<<dim3(64), dim3(256), 0, stream>>>(Wk, Wq, bk, bq, Wbf, bkq);
  kqv_kernel<<<dim3(Tc / 64, Bc), dim3(256), 0, stream>>>(v, Wbf, bkq, kqb, vbf);
  attn_kernel<<<dim3((Tc / QT) * Bc), dim3(512), 0, stream>>>(v, vbf, kqb, gm, out);
}

// Round 14
// 191.014 us; speedup vs baseline: 2.4944x; 1.6509x over previous
//
#include <hip/hip_runtime.h>

#define Bc 16
#define Cc 512
#define Tc 2048
#define QT 128
#define KT 64
#define LTS 66    // kqv LDS transposed-tile row stride (ushort), 64+2 pad

typedef __attribute__((ext_vector_type(8)))  short short8;
typedef __attribute__((ext_vector_type(4)))  float f32x4;
typedef __attribute__((ext_vector_type(16))) float f32x16;
typedef unsigned short u16;

static __device__ __forceinline__ u16 f2bf(float x) {
  unsigned u = __float_as_uint(x);
  u += 0x7FFF + ((u >> 16) & 1);   // RNE
  return (u16)(u >> 16);
}

// Pack 2 f32 -> 2 bf16 in one VALU op (no builtin on gfx950).
static __device__ __forceinline__ unsigned cvt_pk_bf16(float lo, float hi) {
  unsigned r;
  asm("v_cvt_pk_bf16_f32 %0, %1, %2" : "=v"(r) : "v"(lo), "v"(hi));
  return r;
}

// Barrier that waits ONLY on LDS ops (lgkmcnt) — outstanding global loads
// stay in flight across it.
static __device__ __forceinline__ void block_sync_lds() {
  __builtin_amdgcn_sched_barrier(0);
  asm volatile("s_waitcnt lgkmcnt(0)" ::: "memory");
  __builtin_amdgcn_s_barrier();
  __builtin_amdgcn_sched_barrier(0);
}

// ---------------- Kernel 0: W -> bf16 (fused k||q), bias -> bkq ----------------
__global__ __launch_bounds__(256) void prep_kernel(
    const float* __restrict__ Wk, const float* __restrict__ Wq,
    const float* __restrict__ bk, const float* __restrict__ bq,
    u16* __restrict__ Wbf, float* __restrict__ bkq)
{
  int idx  = blockIdx.x * 256 + threadIdx.x;
  int base = idx * 4;
  if (base < 128 * Cc) {
    int ch = base >> 9;
    int c  = base & (Cc - 1);
    const float* src = (ch < 64) ? (Wk + (size_t)ch * Cc + c)
                                 : (Wq + (size_t)(ch - 64) * Cc + c);
    f32x4 w = *reinterpret_cast<const f32x4*>(src);
    uint2 o;
    o.x = (unsigned)f2bf(w[0]) | ((unsigned)f2bf(w[1]) << 16);
    o.y = (unsigned)f2bf(w[2]) | ((unsigned)f2bf(w[3]) << 16);
    *reinterpret_cast<uint2*>(Wbf + base) = o;
  }
  if (idx < 128) bkq[idx] = (idx < 64) ? bk[idx] : bq[idx - 64];
}

// ---------------- Kernel 1: kq[t][ch] via MFMA + vbf16 emission ----------------
__global__ __launch_bounds__(256) void kqv_kernel(
    const float* __restrict__ v, const u16* __restrict__ Wbf,
    const float* __restrict__ bkq, u16* __restrict__ kq, u16* __restrict__ vbf)
{
  __shared__ u16 LDSt[2][64][LTS];
  const int b   = blockIdx.y;
  const int t0  = blockIdx.x * 64;
  const int tid = threadIdx.x;
  const int lane = tid & 63;
  const int w    = tid >> 6;
  const int l15  = lane & 15;
  const int lg   = lane >> 4;

  f32x4 acc[8];
  #pragma unroll
  for (int mt = 0; mt < 8; ++mt) acc[mt] = f32x4{0.f, 0.f, 0.f, 0.f};

  const float* vb = v + (size_t)b * Cc * Tc + t0;
  float x[16];
  #pragma unroll
  for (int r = 0; r < 16; ++r) x[r] = vb[(size_t)(w * 16 + r) * Tc + lane];

  int buf = 0;
  for (int c0 = 0; c0 < Cc; c0 += 64, buf ^= 1) {
    #pragma unroll
    for (int r = 0; r < 16; ++r) {
      u16 hb = f2bf(x[r]);
      LDSt[buf][lane][w * 16 + r] = hb;
      vbf[((size_t)b * Cc + c0 + w * 16 + r) * Tc + t0 + lane] = hb;
    }
    block_sync_lds();
    if (c0 + 64 < Cc) {
      #pragma unroll
      for (int r = 0; r < 16; ++r)
        x[r] = vb[(size_t)(c0 + 64 + w * 16 + r) * Tc + lane];
    }
    #pragma unroll
    for (int ks = 0; ks < 2; ++ks) {
      short8 bfrag = *reinterpret_cast<const short8*>(&LDSt[buf][w * 16 + l15][ks * 32 + lg * 8]);
      #pragma unroll
      for (int mt = 0; mt < 8; ++mt) {
        short8 afrag = *reinterpret_cast<const short8*>(
            Wbf + (size_t)(mt * 16 + l15) * Cc + c0 + ks * 32 + lg * 8);
        acc[mt] = __builtin_amdgcn_mfma_f32_16x16x32_bf16(afrag, bfrag, acc[mt], 0, 0, 0);
      }
    }
  }
  const int t = t0 + w * 16 + l15;
  u16* op = kq + ((size_t)b * Tc + t) * 128;
  #pragma unroll
  for (int mt = 0; mt < 8; ++mt) {
    int chb = mt * 16 + lg * 4;
    uint2 o;
    o.x = cvt_pk_bf16(acc[mt][0] + bkq[chb + 0], acc[mt][1] + bkq[chb + 1]);
    o.y = cvt_pk_bf16(acc[mt][2] + bkq[chb + 2], acc[mt][3] + bkq[chb + 3]);
    *reinterpret_cast<uint2*>(op + chb) = o;
  }
}

// ---------------- Kernel 2: flash attention, fixed-m, swizzled P, 32x32 PV ----------------
// r9 rotated-pipeline structure. P stored [128 j][64 i] bf16, 128 B rows,
// chunk XOR-swizzle (chunk' = chunk ^ (row&7)) -> all LDS ops <=2-way.
// PV uses mfma_f32_32x32x16 (A=V m=c, B=P n=j): 32 MFMA/iter/wave vs 64.
__global__ __launch_bounds__(512, 2) void attn_kernel(
    const float* __restrict__ v, const u16* __restrict__ vbf,
    const u16* __restrict__ kq, const float* __restrict__ gamma_p,
    float* __restrict__ out)
{
  __shared__ u16 P[2][128 * 64];        // 32 KB, swizzled
  __shared__ __align__(16) float ep_lds[8][32 * 36];  // 36.9 KB epilogue transpose
  __shared__ float lsum_lds[QT];
  __shared__ __align__(16) float linv_lds[QT];

  // XCD-aware swizzle: 256 blocks, 8 XCDs -> each XCD sees 2 consecutive b's
  const int L   = blockIdx.x;
  const int lin = (L & 7) * 32 + (L >> 3);
  const int b   = lin >> 4;
  const int j0  = (lin & 15) * QT;
  const int tid = threadIdx.x;
  const int lane = tid & 63;
  const int wid  = tid >> 6;      // 0..7 = owned j-tile (S) AND 64-channel slice (PV)
  const int l15  = lane & 15;
  const int lg   = lane >> 4;     // 0..3
  const int l31  = lane & 31;
  const int kh   = lane >> 5;     // 0..1
  const int c0   = wid * 64;

  // Q B-fragments for S (16x16): n=j=l15, k=d=lg*8+e
  short8 qf0, qf1;
  {
    const u16* qp = kq + (size_t)(b * Tc + j0 + wid * 16 + l15) * 128 + 64 + lg * 8;
    qf0 = *reinterpret_cast<const short8*>(qp);
    qf1 = *reinterpret_cast<const short8*>(qp + 32);
  }

  f32x16 O32[2][4];   // [ct][jt]: D of 32x32 PV; col j=l31, row c via reg map
  #pragma unroll
  for (int a = 0; a < 2; ++a)
    #pragma unroll
    for (int bb = 0; bb < 4; ++bb)
      #pragma unroll
      for (int e = 0; e < 16; ++e) O32[a][bb][e] = 0.f;

  float lsum = 0.f;

  const u16* kbase = kq + (size_t)b * Tc * 128 + lg * 8;
  const u16* vbase = vbf + ((size_t)b * Cc + c0) * Tc;

  short8 kf[4][2];       // K frags for S_{i+1}
  short8 vf0[2][2];      // V A-frags ks 0..1 (i 0..31), prefetched cross-iter
  const int vrow = (size_t)0 + l31;  // lane's V row within 32-row tile

  // ---- prologue: K_0 -> S_0 -> exp_0 -> P_0; prefetch K_1, vf0(i=0) ----
  #pragma unroll
  for (int it = 0; it < 4; ++it) {
    const u16* kp = kbase + (size_t)(it * 16 + l15) * 128;
    kf[it][0] = *reinterpret_cast<const short8*>(kp);
    kf[it][1] = *reinterpret_cast<const short8*>(kp + 32);
  }
  #pragma unroll
  for (int ct = 0; ct < 2; ++ct)
    #pragma unroll
    for (int kk = 0; kk < 2; ++kk)
      vf0[ct][kk] = *reinterpret_cast<const short8*>(
          vbase + (size_t)(ct * 32 + vrow) * Tc + kk * 16 + kh * 8);
  {
    f32x4 sacc[4];
    #pragma unroll
    for (int it = 0; it < 4; ++it) {
      f32x4 s = f32x4{0.f, 0.f, 0.f, 0.f};
      s = __builtin_amdgcn_mfma_f32_16x16x32_bf16(kf[it][0], qf0, s, 0, 0, 0);
      s = __builtin_amdgcn_mfma_f32_16x16x32_bf16(kf[it][1], qf1, s, 0, 0, 0);
      sacc[it] = s;
    }
    u16* prow = &P[0][(wid * 16 + l15) * 64];
    #pragma unroll
    for (int it = 0; it < 4; ++it) {
      float p0 = __expf(sacc[it][0]);
      float p1 = __expf(sacc[it][1]);
      float p2 = __expf(sacc[it][2]);
      float p3 = __expf(sacc[it][3]);
      lsum += (p0 + p1) + (p2 + p3);
      uint2 wv;
      wv.x = cvt_pk_bf16(p0, p1);
      wv.y = cvt_pk_bf16(p2, p3);
      int chk = ((it * 2 + (lg >> 1)) ^ (l15 & 7)) * 8 + (lg & 1) * 4;
      *reinterpret_cast<uint2*>(prow + chk) = wv;
    }
  }
  #pragma unroll
  for (int it = 0; it < 4; ++it) {
    const u16* kp = kbase + (size_t)(KT + it * 16 + l15) * 128;
    kf[it][0] = *reinterpret_cast<const short8*>(kp);
    kf[it][1] = *reinterpret_cast<const short8*>(kp + 32);
  }
  block_sync_lds();

  int pb = 0;
  for (int i0 = 0; i0 < Tc; i0 += KT, pb ^= 1) {
    const bool last = (i0 + KT >= Tc);

    // ---- V A-frags ks 2..3 for tile i: issued early ----
    short8 vf1[2][2];
    #pragma unroll
    for (int ct = 0; ct < 2; ++ct)
      #pragma unroll
      for (int kk = 0; kk < 2; ++kk)
        vf1[ct][kk] = *reinterpret_cast<const short8*>(
            vbase + (size_t)(ct * 32 + vrow) * Tc + i0 + 32 + kk * 16 + kh * 8);

    // ---- S_{i+1} + exp + publish P_{i+1} (sacc dies here) ----
    if (!last) {
      f32x4 sacc[4];
      #pragma unroll
      for (int it = 0; it < 4; ++it) {
        f32x4 s = f32x4{0.f, 0.f, 0.f, 0.f};
        s = __builtin_amdgcn_mfma_f32_16x16x32_bf16(kf[it][0], qf0, s, 0, 0, 0);
        s = __builtin_amdgcn_mfma_f32_16x16x32_bf16(kf[it][1], qf1, s, 0, 0, 0);
        sacc[it] = s;
      }
      u16* prow = &P[pb ^ 1][(wid * 16 + l15) * 64];
      #pragma unroll
      for (int it = 0; it < 4; ++it) {
        float p0 = __expf(sacc[it][0]);
        float p1 = __expf(sacc[it][1]);
        float p2 = __expf(sacc[it][2]);
        float p3 = __expf(sacc[it][3]);
        lsum += (p0 + p1) + (p2 + p3);
        uint2 wv;
        wv.x = cvt_pk_bf16(p0, p1);
        wv.y = cvt_pk_bf16(p2, p3);
        int chk = ((it * 2 + (lg >> 1)) ^ (l15 & 7)) * 8 + (lg & 1) * 4;
        *reinterpret_cast<uint2*>(prow + chk) = wv;
      }
    }

    // ---- PV_i: O[c][j] += V[c,i] P[i,j] via 32x32x16 ----
    #pragma unroll
    for (int ks = 0; ks < 4; ++ks) {
      short8 pf[4];
      #pragma unroll
      for (int jt = 0; jt < 4; ++jt) {
        int row = jt * 32 + l31;
        int chk = ((ks * 2 + kh) ^ (row & 7)) * 8;
        pf[jt] = *reinterpret_cast<const short8*>(&P[pb][row * 64 + chk]);
      }
      const short8* vsel0 = (ks < 2) ? &vf0[0][ks] : &vf1[0][ks - 2];
      const short8* vsel1 = (ks < 2) ? &vf0[1][ks] : &vf1[1][ks - 2];
      #pragma unroll
      for (int jt = 0; jt < 4; ++jt) {
        O32[0][jt] = __builtin_amdgcn_mfma_f32_32x32x16_bf16(*vsel0, pf[jt], O32[0][jt], 0, 0, 0);
        O32[1][jt] = __builtin_amdgcn_mfma_f32_32x32x16_bf16(*vsel1, pf[jt], O32[1][jt], 0, 0, 0);
      }
    }

    // ---- prefetch K_{i+2} (kf dead during PV) and vf0_{i+1} ----
    if (!last) {
      if (i0 + 2 * KT < Tc) {
        #pragma unroll
        for (int it = 0; it < 4; ++it) {
          const u16* kp = kbase + (size_t)(i0 + 2 * KT + it * 16 + l15) * 128;
          kf[it][0] = *reinterpret_cast<const short8*>(kp);
          kf[it][1] = *reinterpret_cast<const short8*>(kp + 32);
        }
      }
      #pragma unroll
      for (int ct = 0; ct < 2; ++ct)
        #pragma unroll
        for (int kk = 0; kk < 2; ++kk)
          vf0[ct][kk] = *reinterpret_cast<const short8*>(
              vbase + (size_t)(ct * 32 + vrow) * Tc + (i0 + KT) + kk * 16 + kh * 8);
      block_sync_lds();
    }
  }

  // ---- denominators ----
  lsum += __shfl_xor(lsum, 16);
  lsum += __shfl_xor(lsum, 32);
  if (lane < 16) lsum_lds[wid * 16 + lane] = lsum;
  __syncthreads();
  const float gamma = *gamma_p;
  if (tid < QT) linv_lds[tid] = gamma / lsum_lds[tid];
  __syncthreads();

  // ---- epilogue: per-wave LDS transpose of each 32x32 tile, float4 I/O ----
  float* ep = ep_lds[wid];
  const int rd_row = lane >> 3;   // 0..7 (+8h)
  const int rd_ch  = lane & 7;    // j quad
  #pragma unroll
  for (int ct = 0; ct < 2; ++ct) {
    #pragma unroll
    for (int jt = 0; jt < 4; ++jt) {
      // stage: lane (l31=j, kh) holds c rows (reg&3)+8*(reg>>2)+4*kh
      #pragma unroll
      for (int reg = 0; reg < 16; ++reg) {
        int cl = (reg & 3) + 8 * (reg >> 2) + 4 * kh;
        ep[cl * 36 + l31] = O32[ct][jt][reg];
      }
      asm volatile("s_waitcnt lgkmcnt(0)" ::: "memory");
      __builtin_amdgcn_sched_barrier(0);
      #pragma unroll
      for (int h = 0; h < 4; ++h) {
        const int row = rd_row + 8 * h;
        f32x4 o4 = *reinterpret_cast<const f32x4*>(&ep[row * 36 + rd_ch * 4]);
        const int jg = jt * 32 + rd_ch * 4;
        f32x4 li = *reinterpret_cast<const f32x4*>(&linv_lds[jg]);
        const int c_glob = c0 + ct * 32 + row;
        const float* vr = v + ((size_t)(b * Cc + c_glob)) * Tc + j0 + jg;
        float* orow = out + ((size_t)(b * Cc + c_glob)) * Tc + j0 + jg;
        f32x4 v4 = *reinterpret_cast<const f32x4*>(vr);
        f32x4 o;
        o[0] = v4[0] + li[0] * o4[0];
        o[1] = v4[1] + li[1] * o4[1];
        o[2] = v4[2] + li[2] * o4[2];
        o[3] = v4[3] + li[3] * o4[3];
        *reinterpret_cast<f32x4*>(orow) = o;
      }
      asm volatile("s_waitcnt lgkmcnt(0)" ::: "memory");
      __builtin_amdgcn_sched_barrier(0);
    }
  }
}

extern "C" void kernel_launch(void* const* d_in, const int* in_sizes, int n_in,
                              void* d_out, int out_size, void* d_ws, size_t ws_size,
                              hipStream_t stream) {
  const float* v  = (const float*)d_in[0];
  const float* Wk = (const float*)d_in[1];
  const float* bk = (const float*)d_in[2];
  const float* Wq = (const float*)d_in[3];
  const float* bq = (const float*)d_in[4];
  const float* gm = (const float*)d_in[5];
  float* out = (float*)d_out;

  char* ws = (char*)d_ws;
  u16*   kqb = (u16*)ws;                                   //  8,388,608 B
  u16*   vbf = (u16*)(ws + 8388608);                       // 33,554,432 B
  u16*   Wbf = (u16*)(ws + 8388608 + 33554432);            //    131,072 B
  float* bkq = (float*)(ws + 8388608 + 33554432 + 131072); //        512 B

  prep_kernel<<<dim3(64), dim3(256), 0, stream>>>(Wk, Wq, bk, bq, Wbf, bkq);
  kqv_kernel<<<dim3(Tc / 64, Bc), dim3(256), 0, stream>>>(v, Wbf, bkq, kqb, vbf);
  attn_kernel<<<dim3((Tc / QT) * Bc), dim3(512), 0, stream>>>(v, vbf, kqb, gm, out);
}